// Round 2
// baseline (257.200 us; speedup 1.0000x reference)
//
#include <hip/hip_runtime.h>

#define NB 32
#define NC 511      // T-1 context positions
#define NK 8        // senses (center)
#define NS 8        // senses (context)
#define ND 300      // embedding dim
#define ND4 75      // float4 per row
#define NCG 32      // c-groups (chunks of CPB) for m-tilde partials
#define CPB 16      // c's per block (8 waves x 2)
#define EPS_COS 1e-8f

// Math notes (verified R1-R6, absmax 0.0):
//  - positional log-weight is constant (dist>=1 -> exp(-1000*d) underflows ->
//    log(EPS)), cancels in softmax over c => center_pos/query_token_ids unused.
//  - cosine(cen,m) is scale-invariant in m => softmax normalization and max-
//    subtraction cancel; accumulate unnormalized m~ = sum_c exp(a_c) * v_c.
//  - R10 theory: timed window includes ~2x 628MB ws-poison fills (~184 us
//    fixed, visible in rocprof at 92 us each); our kernels are only ~55 us.
//    => cut kernel share: fuse K1+K2 (v round-trip 39MB and ea 1MB eliminated;
//    m~ chunk-partials accumulated in registers + one LDS reduce per block),
//    fuse K3a+K3b. Pipeline: 2 kernels, ~167 MB total traffic.

typedef float nfloat4 __attribute__((ext_vector_type(4)));

__device__ __forceinline__ void n4add(nfloat4& a, const nfloat4& b) { a += b; }

// ---------------------------------------------------------------------------
// K1: block = (b, cg) = 16 consecutive c's; 8 waves x 2 c's each (consecutive
// pair -> summation order stays near-sequential). Per c: batched NT loads ->
// tree mean -> v (registers only); 8 dots vs cen; distributed butterfly; exp;
// broadcast ea[0..7] to all lanes; FMA into per-wave m~ accumulator.
// End of block: LDS reduce over 8 waves -> part[b][k][cg][d].
// Reads ctx once (157 MB) — the BW-critical pass. No v/ea global traffic.
// ---------------------------------------------------------------------------
__global__ __launch_bounds__(512) void k_vam(const float* __restrict__ ctx,
                                             const float* __restrict__ cen,
                                             float* __restrict__ part) {
    const int b    = blockIdx.x >> 5;        // 32 cgroups per b
    const int cg   = blockIdx.x & 31;
    const int w    = threadIdx.x >> 6;       // 8 waves
    const int lane = threadIdx.x & 63;
    const int i0 = lane;
    const int i1 = lane + 64;
    const bool has1 = (i1 < ND4);            // lanes 0..10 own a second float4

    const nfloat4* cen4 = (const nfloat4*)cen + (size_t)b * NK * ND4;

    nfloat4 macc0[NK] = {};                  // m~ partial, d = 4*i0..4*i0+3
    nfloat4 macc1[NK] = {};                  // m~ partial, d = 4*i1.. (lanes<11)

#pragma unroll
    for (int cc = 0; cc < 2; ++cc) {
        const int c = cg * CPB + 2 * w + cc; // wave-uniform
        if (c >= NC) break;                  // only block cg=31, wave 7, cc=1

        const nfloat4* ctx4 = (const nfloat4*)ctx + (size_t)(b * NC + c) * NS * ND4;

        // ---- batched NT loads: 8 unmasked, then one exec-toggle block of 8 ----
        nfloat4 X[NS];
#pragma unroll
        for (int s = 0; s < NS; ++s)
            X[s] = __builtin_nontemporal_load(&ctx4[s * ND4 + i0]);
        nfloat4 Y[NS] = {};                  // stays 0 for lanes >= 11
        if (has1) {
#pragma unroll
            for (int s = 0; s < NS; ++s)
                Y[s] = __builtin_nontemporal_load(&ctx4[s * ND4 + i1]);
        }

        // ---- tree mean over senses ----
        n4add(X[0], X[1]); n4add(X[2], X[3]); n4add(X[4], X[5]); n4add(X[6], X[7]);
        n4add(X[0], X[2]); n4add(X[4], X[6]);
        n4add(X[0], X[4]);
        n4add(Y[0], Y[1]); n4add(Y[2], Y[3]); n4add(Y[4], Y[5]); n4add(Y[6], Y[7]);
        n4add(Y[0], Y[2]); n4add(Y[4], Y[6]);
        n4add(Y[0], Y[4]);
        const float inv = 0.125f;            // 1/S
        nfloat4 s0 = X[0] * inv;
        nfloat4 s1 = Y[0] * inv;             // zero beyond lane 10

        // ---- 8 dots vs cen (L1-resident after first c) ----
        float pk[NK];
#pragma unroll
        for (int k = 0; k < NK; ++k) {
            nfloat4 ca = cen4[k * ND4 + i0];
            float p = ca.x * s0.x + ca.y * s0.y + ca.z * s0.z + ca.w * s0.w;
            if (has1) {
                nfloat4 cb = cen4[k * ND4 + i1];
                p += cb.x * s1.x + cb.y * s1.y + cb.z * s1.z + cb.w * s1.w;
            }
            pk[k] = p;
        }

        // ---- distributed exchange-butterfly: lane l -> total for k = l&7 ----
        const bool b0 = (lane & 1) != 0;
        float r[4];
#pragma unroll
        for (int j = 0; j < 4; ++j) {
            float keep = b0 ? pk[2 * j + 1] : pk[2 * j];
            float send = b0 ? pk[2 * j]     : pk[2 * j + 1];
            r[j] = keep + __shfl_xor(send, 1);
        }
        const bool b1 = (lane & 2) != 0;
        float q0, q1;
        { float keep = b1 ? r[1] : r[0]; float send = b1 ? r[0] : r[1];
          q0 = keep + __shfl_xor(send, 2); }
        { float keep = b1 ? r[3] : r[2]; float send = b1 ? r[2] : r[3];
          q1 = keep + __shfl_xor(send, 2); }
        const bool b2 = (lane & 4) != 0;
        float u;
        { float keep = b2 ? q1 : q0; float send = b2 ? q0 : q1;
          u = keep + __shfl_xor(send, 4); }
        u += __shfl_xor(u, 8);
        u += __shfl_xor(u, 16);
        u += __shfl_xor(u, 32);

        const float scale = 0.057735026919f; // 1/sqrt(300)
        float e = __expf(u * scale);         // lane l holds ea for k=l&7

        // ---- broadcast ea[0..7] from lanes 0..7 ----
        float eav[NK];
#pragma unroll
        for (int k = 0; k < NK; ++k) eav[k] = __shfl(e, k);

        // ---- accumulate m~ partial: macc[k] += ea[k] * v ----
#pragma unroll
        for (int k = 0; k < NK; ++k) {
            macc0[k] += eav[k] * s0;
            macc1[k] += eav[k] * s1;         // s1==0 for lanes>=11: harmless
        }
    }

    // ---- block reduce over 8 waves via LDS, then one coalesced part write ----
    __shared__ float pl[8][NK][ND4 * 4 + 4];   // [wave][k][304] (pad vs conflicts)
#pragma unroll
    for (int k = 0; k < NK; ++k) {
        ((nfloat4*)pl[w][k])[i0] = macc0[k];
        if (has1) ((nfloat4*)pl[w][k])[i1] = macc1[k];
    }
    __syncthreads();

    for (int idx = threadIdx.x; idx < NK * ND; idx += 512) {
        const int k = idx / ND;
        const int d = idx - k * ND;
        float s = 0.f;
#pragma unroll
        for (int ww = 0; ww < 8; ++ww) s += pl[ww][k][d];   // c-ascending order
        part[(((size_t)b * NK + k) * NCG + cg) * ND + d] = s;
    }
}

// ---------------------------------------------------------------------------
// K2: per b — wave w owns k=w: sum the 32 m~ chunk-partials along d (contiguous
// [NCG][ND] panel per (b,k)), cosine vs cen row, then softmax/argmax/pooled.
// ---------------------------------------------------------------------------
__global__ __launch_bounds__(512) void k_fin2(const float* __restrict__ part,
                                              const float* __restrict__ cen,
                                              float* __restrict__ out) {
    const int b    = blockIdx.x;
    const int w    = threadIdx.x >> 6;       // = k
    const int lane = threadIdx.x & 63;
    __shared__ float sred[NK];
    __shared__ int bidx;

    const float* pp = part + ((size_t)b * NK + w) * NCG * ND;
    const float* cp = cen + (size_t)(b * NK + w) * ND;
    float num = 0.f, n1 = 0.f, n2 = 0.f;
    for (int d = lane; d < ND; d += 64) {
        float mval = 0.f;
#pragma unroll
        for (int cg = 0; cg < NCG; ++cg) mval += pp[cg * ND + d];
        float cv = cp[d];
        num += cv * mval; n1 += cv * cv; n2 += mval * mval;
    }
#pragma unroll
    for (int off = 32; off; off >>= 1) {
        num += __shfl_down(num, off);
        n1  += __shfl_down(n1, off);
        n2  += __shfl_down(n2, off);
    }
    if (lane == 0) {
        float denom = fmaxf(sqrtf(n1), EPS_COS) * fmaxf(sqrtf(n2), EPS_COS);
        sred[w] = num / denom;
    }
    __syncthreads();

    if (threadIdx.x == 0) {
        float mx = sred[0];
#pragma unroll
        for (int k = 1; k < NK; ++k) mx = fmaxf(mx, sred[k]);
        float e[NK], sum = 0.f;
#pragma unroll
        for (int k = 0; k < NK; ++k) { e[k] = __expf(sred[k] - mx); sum += e[k]; }
        float invs = 1.f / sum;
        int best = 0; float bv = sred[0];
#pragma unroll
        for (int k = 1; k < NK; ++k) if (sred[k] > bv) { bv = sred[k]; best = k; }
#pragma unroll
        for (int k = 0; k < NK; ++k)
            out[(size_t)NB * ND + b * NK + k] = e[k] * invs;
        bidx = best;
    }
    __syncthreads();

    const float* src = cen + (size_t)(b * NK + bidx) * ND;
    for (int idx = threadIdx.x; idx < ND; idx += 512)
        out[(size_t)b * ND + idx] = src[idx];
}

extern "C" void kernel_launch(void* const* d_in, const int* in_sizes, int n_in,
                              void* d_out, int out_size, void* d_ws, size_t ws_size,
                              hipStream_t stream) {
    // d_in[0]=center_pos, d_in[1]=query_token_ids: unused (log-weight constant)
    const float* cen = (const float*)d_in[2];   // [B,K,d]
    const float* ctx = (const float*)d_in[3];   // [B,C,S,d]
    float* out = (float*)d_out;                 // pooled [B,d] then q [B,K]

    float* part = (float*)d_ws;                 // [B][K][NCG][ND] = 9.8 MB

    k_vam<<<dim3(NB * NCG), dim3(512), 0, stream>>>(ctx, cen, part);
    k_fin2<<<dim3(NB), dim3(512), 0, stream>>>(part, cen, out);
}

// Round 3
// 238.652 us; speedup vs baseline: 1.0777x; 1.0777x over previous
//
#include <hip/hip_runtime.h>

#define NB 32
#define NC 511      // T-1 context positions
#define NK 8        // senses (center)
#define NS 8        // senses (context)
#define ND 300      // embedding dim
#define ND4 75      // float4 per row
#define NCG 16      // c-groups per b (32 c's per block)
#define GPB 8       // sub-groups of 4 c's per block
#define EPS_COS 1e-8f

// Math notes (verified R1-R6, absmax 0.0):
//  - positional log-weight is constant (dist>=1 -> exp(-1000*d) underflows ->
//    log(EPS)), cancels in softmax over c => center_pos/query_token_ids unused.
//  - cosine(cen,m) is scale-invariant in m => softmax normalization and max-
//    subtraction cancel; accumulate unnormalized m~ = sum_c exp(a_c) * v_c.
//  - R10 post-mortem: timed window = ~184us fixed ws-poison fills + kernels
//    (R9 kernels ~58us, R10 ~73us). R10's register-fused k_vam regressed:
//    64 VGPR acc + hoisted cen (+64) -> occupancy cliff -> NT stream exposed.
//  - R11: fuse via LDS instead. Phase 1 per 4-c group = exact R9 k_va body
//    (v -> LDS tile, ea -> LDS); phase 2 = k_m-style per-d scalar accumulate
//    (8 regs). VGPR<128, LDS ~5KB, 4-wave blocks, memory clobber per group
//    stops cen-load hoisting. v/ea global traffic eliminated; part = 4.9MB.

typedef float nfloat4 __attribute__((ext_vector_type(4)));

__device__ __forceinline__ void n4add(nfloat4& a, const nfloat4& b) { a += b; }

// ---------------------------------------------------------------------------
// K1: block = (b, cg) owns 32 consecutive c's, processed as 8 groups of 4
// (wave w -> c = base+w). Per group: batched NT loads -> tree mean -> v tile
// in LDS; 8 dots vs cen; distributed butterfly; ea[0..7] -> LDS; barrier;
// per-d scalar m~ accumulation over the 4 c's; barrier. After 8 groups, one
// coalesced part write. Reads ctx once (157 MB) — the BW-critical pass.
// ---------------------------------------------------------------------------
__global__ __launch_bounds__(256, 4) void k_vam(const float* __restrict__ ctx,
                                                const float* __restrict__ cen,
                                                float* __restrict__ part) {
    const int b    = blockIdx.x >> 4;        // 16 cgroups per b
    const int cg   = blockIdx.x & 15;
    const int w    = threadIdx.x >> 6;       // 4 waves
    const int lane = threadIdx.x & 63;
    const int t    = threadIdx.x;
    const int i0 = lane;
    const int i1 = lane + 64;
    const bool has1  = (i1 < ND4);           // lanes 0..10 own a second float4
    const bool hasd1 = (t < ND - 256);       // threads 0..43 own d = 256+t

    __shared__ float vl[4][ND4 * 4 + 4];     // v tile, padded rows (16B-aligned)
    __shared__ float al[4][NK];              // ea tile

    const nfloat4* cen4 = (const nfloat4*)cen + (size_t)b * NK * ND4;

    float acc0[NK] = {};                     // m~ partial at d = t
    float acc1[NK] = {};                     // m~ partial at d = 256+t (t<44)

    const int cbase0 = cg * 32;

    for (int g = 0; g < GPB; ++g) {
        const int cbase = cbase0 + g * 4;
        const int cn = min(4, NC - cbase);   // 3 only for (cg=15, g=7)
        const int c = cbase + w;

        if (c < NC) {                        // wave-uniform
            const nfloat4* ctx4 =
                (const nfloat4*)ctx + (size_t)(b * NC + c) * NS * ND4;

            // ---- batched NT loads: 8 unmasked + one exec-toggle block of 8 ----
            nfloat4 X[NS];
#pragma unroll
            for (int s = 0; s < NS; ++s)
                X[s] = __builtin_nontemporal_load(&ctx4[s * ND4 + i0]);
            nfloat4 Y[NS] = {};              // stays 0 for lanes >= 11
            if (has1) {
#pragma unroll
                for (int s = 0; s < NS; ++s)
                    Y[s] = __builtin_nontemporal_load(&ctx4[s * ND4 + i1]);
            }

            // ---- tree mean over senses ----
            n4add(X[0], X[1]); n4add(X[2], X[3]); n4add(X[4], X[5]); n4add(X[6], X[7]);
            n4add(X[0], X[2]); n4add(X[4], X[6]);
            n4add(X[0], X[4]);
            n4add(Y[0], Y[1]); n4add(Y[2], Y[3]); n4add(Y[4], Y[5]); n4add(Y[6], Y[7]);
            n4add(Y[0], Y[2]); n4add(Y[4], Y[6]);
            n4add(Y[0], Y[4]);
            const float inv = 0.125f;        // 1/S
            nfloat4 s0 = X[0] * inv;
            nfloat4 s1 = Y[0] * inv;         // zero beyond lane 10

            // ---- v -> LDS tile ----
            ((nfloat4*)vl[w])[i0] = s0;
            if (has1) ((nfloat4*)vl[w])[i1] = s1;

            // ---- 8 dots vs cen (L1-resident; reloaded per group, see clobber) ----
            float pk[NK];
#pragma unroll
            for (int k = 0; k < NK; ++k) {
                nfloat4 ca = cen4[k * ND4 + i0];
                float p = ca.x * s0.x + ca.y * s0.y + ca.z * s0.z + ca.w * s0.w;
                if (has1) {
                    nfloat4 cb = cen4[k * ND4 + i1];
                    p += cb.x * s1.x + cb.y * s1.y + cb.z * s1.z + cb.w * s1.w;
                }
                pk[k] = p;
            }

            // ---- distributed exchange-butterfly: lane l -> total for k=l&7 ----
            const bool b0 = (lane & 1) != 0;
            float r[4];
#pragma unroll
            for (int j = 0; j < 4; ++j) {
                float keep = b0 ? pk[2 * j + 1] : pk[2 * j];
                float send = b0 ? pk[2 * j]     : pk[2 * j + 1];
                r[j] = keep + __shfl_xor(send, 1);
            }
            const bool b1 = (lane & 2) != 0;
            float q0, q1;
            { float keep = b1 ? r[1] : r[0]; float send = b1 ? r[0] : r[1];
              q0 = keep + __shfl_xor(send, 2); }
            { float keep = b1 ? r[3] : r[2]; float send = b1 ? r[2] : r[3];
              q1 = keep + __shfl_xor(send, 2); }
            const bool b2 = (lane & 4) != 0;
            float u;
            { float keep = b2 ? q1 : q0; float send = b2 ? q0 : q1;
              u = keep + __shfl_xor(send, 4); }
            u += __shfl_xor(u, 8);
            u += __shfl_xor(u, 16);
            u += __shfl_xor(u, 32);

            if (lane < NK) {
                const float scale = 0.057735026919f; // 1/sqrt(300)
                al[w][lane] = __expf(u * scale);
            }
        }
        __syncthreads();

        // ---- phase 2: per-d scalar m~ accumulation (c ascending) ----
        for (int cc = 0; cc < cn; ++cc) {
            float vv0 = vl[cc][t];
#pragma unroll
            for (int k = 0; k < NK; ++k) acc0[k] += al[cc][k] * vv0;
        }
        if (hasd1) {
            for (int cc = 0; cc < cn; ++cc) {
                float vv1 = vl[cc][256 + t];
#pragma unroll
                for (int k = 0; k < NK; ++k) acc1[k] += al[cc][k] * vv1;
            }
        }
        __syncthreads();
        // stop cen/ctx address + cen-fragment hoisting across groups (keeps
        // VGPR pressure at the single-group level; cen stays L1-warm anyway)
        asm volatile("" ::: "memory");
    }

    // ---- one coalesced part write per k ----
#pragma unroll
    for (int k = 0; k < NK; ++k) {
        float* pp = part + (((size_t)(b * NK + k)) * NCG + cg) * ND;
        pp[t] = acc0[k];
        if (hasd1) pp[256 + t] = acc1[k];
    }
}

// ---------------------------------------------------------------------------
// K2: per b — wave w owns k=w: sum the 16 m~ chunk-partials along d (contiguous
// [NCG][ND] panel per (b,k)), cosine vs cen row, then softmax/argmax/pooled.
// ---------------------------------------------------------------------------
__global__ __launch_bounds__(512) void k_fin2(const float* __restrict__ part,
                                              const float* __restrict__ cen,
                                              float* __restrict__ out) {
    const int b    = blockIdx.x;
    const int w    = threadIdx.x >> 6;       // = k
    const int lane = threadIdx.x & 63;
    __shared__ float sred[NK];
    __shared__ int bidx;

    const float* pp = part + ((size_t)b * NK + w) * NCG * ND;
    const float* cp = cen + (size_t)(b * NK + w) * ND;
    float num = 0.f, n1 = 0.f, n2 = 0.f;
    for (int d = lane; d < ND; d += 64) {
        float mval = 0.f;
#pragma unroll
        for (int cg = 0; cg < NCG; ++cg) mval += pp[cg * ND + d];
        float cv = cp[d];
        num += cv * mval; n1 += cv * cv; n2 += mval * mval;
    }
#pragma unroll
    for (int off = 32; off; off >>= 1) {
        num += __shfl_down(num, off);
        n1  += __shfl_down(n1, off);
        n2  += __shfl_down(n2, off);
    }
    if (lane == 0) {
        float denom = fmaxf(sqrtf(n1), EPS_COS) * fmaxf(sqrtf(n2), EPS_COS);
        sred[w] = num / denom;
    }
    __syncthreads();

    if (threadIdx.x == 0) {
        float mx = sred[0];
#pragma unroll
        for (int k = 1; k < NK; ++k) mx = fmaxf(mx, sred[k]);
        float e[NK], sum = 0.f;
#pragma unroll
        for (int k = 0; k < NK; ++k) { e[k] = __expf(sred[k] - mx); sum += e[k]; }
        float invs = 1.f / sum;
        int best = 0; float bv = sred[0];
#pragma unroll
        for (int k = 1; k < NK; ++k) if (sred[k] > bv) { bv = sred[k]; best = k; }
#pragma unroll
        for (int k = 0; k < NK; ++k)
            out[(size_t)NB * ND + b * NK + k] = e[k] * invs;
        bidx = best;
    }
    __syncthreads();

    const float* src = cen + (size_t)(b * NK + bidx) * ND;
    for (int idx = threadIdx.x; idx < ND; idx += 512)
        out[(size_t)b * ND + idx] = src[idx];
}

extern "C" void kernel_launch(void* const* d_in, const int* in_sizes, int n_in,
                              void* d_out, int out_size, void* d_ws, size_t ws_size,
                              hipStream_t stream) {
    // d_in[0]=center_pos, d_in[1]=query_token_ids: unused (log-weight constant)
    const float* cen = (const float*)d_in[2];   // [B,K,d]
    const float* ctx = (const float*)d_in[3];   // [B,C,S,d]
    float* out = (float*)d_out;                 // pooled [B,d] then q [B,K]

    float* part = (float*)d_ws;                 // [B][K][NCG][ND] = 4.9 MB

    k_vam<<<dim3(NB * NCG), dim3(256), 0, stream>>>(ctx, cen, part);
    k_fin2<<<dim3(NB), dim3(512), 0, stream>>>(part, cen, out);
}